// Round 9
// baseline (2176.472 us; speedup 1.0000x reference)
//
#include <hip/hip_runtime.h>
#include <cmath>

#define D 64
#define HD 128
#define K1 192
#define TT 8192
#define BBATCH 32
#define RULES 4

typedef _Float16 f16x8 __attribute__((ext_vector_type(8)));
typedef _Float16 f16x4 __attribute__((ext_vector_type(4)));
typedef float f32x4 __attribute__((ext_vector_type(4)));

__device__ __forceinline__ float gelu_exact(float x) {
    return 0.5f * x * (1.0f + erff(x * 0.70710678118654752f));
}

__device__ __forceinline__ float fast_rcp(float x) { return __builtin_amdgcn_rcpf(x); }
__device__ __forceinline__ float fast_exp2(float x) { return __builtin_amdgcn_exp2f(x); }

// tanh-approx GELU (R8, passing): ~6 VALU + 2 trans.
__device__ __forceinline__ float gelu_tanh(float x) {
    float x2 = x * x;
    float t = x * fmaf(x2, -0.10294443f, -2.30220820f);
    return x * fast_rcp(1.0f + fast_exp2(t));
}
// tanh(x) = 1 - 2/(exp2(2*log2e*x)+1) ; exact identity, saturates cleanly
__device__ __forceinline__ float fast_tanh(float x) {
    float e = fast_exp2(x * 2.8853900817779268f);
    return 1.0f - 2.0f * fast_rcp(e + 1.0f);
}

__device__ __forceinline__ f16x4 cvt4_rne(float a, float b, float c, float d) {
    f16x4 r;
    r[0] = (_Float16)a; r[1] = (_Float16)b;
    r[2] = (_Float16)c; r[3] = (_Float16)d;
    return r;
}

// ---------------------------------------------------------------------------
// Control kernel: rule_weights[4], alpha, n_evolve  -> ctrl[0..5]
// ---------------------------------------------------------------------------
__global__ void control_kernel(
    const float* __restrict__ c_state,
    const float* __restrict__ sel_w1, const float* __restrict__ sel_b1,
    const float* __restrict__ sel_w2, const float* __restrict__ sel_b2,
    const float* __restrict__ st_w1,  const float* __restrict__ st_b1,
    const float* __restrict__ st_w2,  const float* __restrict__ st_b2,
    const float* __restrict__ res_w1, const float* __restrict__ res_b1,
    const float* __restrict__ res_w2, const float* __restrict__ res_b2,
    float* __restrict__ ctrl)
{
    __shared__ float cs[128];
    __shared__ float h1s[64], h2s[32], h3s[32];
    __shared__ float lg[12];
    int l = threadIdx.x;  // 64 threads
    cs[l] = c_state[l];
    cs[l + 64] = c_state[l + 64];
    __syncthreads();
    {
        float a = sel_b1[l];
        for (int k = 0; k < 128; ++k) a += cs[k] * sel_w1[k * 64 + l];
        h1s[l] = gelu_exact(a);
    }
    if (l < 32) {
        float a = st_b1[l];
        for (int k = 0; k < 128; ++k) a += cs[k] * st_w1[k * 32 + l];
        h2s[l] = gelu_exact(a);
        float a2 = res_b1[l];
        for (int k = 0; k < 128; ++k) a2 += cs[k] * res_w1[k * 32 + l];
        h3s[l] = gelu_exact(a2);
    }
    __syncthreads();
    if (l < 4) {
        float a = sel_b2[l];
        for (int j = 0; j < 64; ++j) a += h1s[j] * sel_w2[j * 4 + l];
        lg[l] = a;
    }
    if (l >= 8 && l < 15) {
        int s = l - 8;
        float a = st_b2[s];
        for (int j = 0; j < 32; ++j) a += h2s[j] * st_w2[j * 7 + s];
        lg[4 + s] = a;
    }
    if (l == 32) {
        float a = res_b2[0];
        for (int j = 0; j < 32; ++j) a += h3s[j] * res_w2[j];
        lg[11] = a;
    }
    __syncthreads();
    if (l == 0) {
        float m = fmaxf(fmaxf(lg[0], lg[1]), fmaxf(lg[2], lg[3]));
        float e0 = expf(lg[0] - m), e1 = expf(lg[1] - m);
        float e2 = expf(lg[2] - m), e3 = expf(lg[3] - m);
        float s = e0 + e1 + e2 + e3;
        ctrl[0] = e0 / s; ctrl[1] = e1 / s; ctrl[2] = e2 / s; ctrl[3] = e3 / s;
        float m2 = lg[4];
        for (int i = 1; i < 7; ++i) m2 = fmaxf(m2, lg[4 + i]);
        float ss = 0.f, es[7];
        for (int i = 0; i < 7; ++i) { es[i] = expf(lg[4 + i] - m2); ss += es[i]; }
        float nsoft = 0.f;
        for (int i = 0; i < 7; ++i) nsoft += (es[i] / ss) * (float)(i + 2);
        int n = (int)(nsoft + 0.5f);
        n = n < 2 ? 2 : (n > 8 ? 8 : n);
        float alpha = 0.1f + 0.8f / (1.0f + expf(-lg[11]));
        ctrl[4] = alpha;
        ctrl[5] = (float)n;
    }
}

// ---------------------------------------------------------------------------
// Prep kernel (unchanged layouts — verified R4-R8):
//   w1b: A-fragments of W1^T  [ks(6)][htile(32, = r*8+ht)][lane][8]
//   w2b: A-fragments of W2^T  [r][ks2][dtile(4)][lane][8]
// ---------------------------------------------------------------------------
__global__ __launch_bounds__(256) void prep_kernel(
    const float* __restrict__ rule_w1, const float* __restrict__ rule_w2,
    _Float16* __restrict__ w1b, _Float16* __restrict__ w2b)
{
    int t = blockIdx.x * 256 + threadIdx.x;
    if (t < 12288) {
        int lane = t & 63;
        int x = t >> 6;          // 0..191
        int htile = x & 31;      // global h tile (r = htile>>3)
        int ks = x >> 5;         // 0..5
        int r = htile >> 3;
        int h128 = (htile & 7) * 16 + (lane & 15);
        int kbase = ks * 32 + (lane >> 4) * 8;
        f16x8 v;
#pragma unroll
        for (int j = 0; j < 8; ++j)
            v[j] = (_Float16)rule_w1[((size_t)r * K1 + kbase + j) * HD + h128];
        ((f16x8*)w1b)[(ks * 32 + htile) * 64 + lane] = v;
    } else if (t < 12288 + 4096) {
        int u = t - 12288;
        int lane = u & 63;
        int mt = (u >> 6) & 3;   // d tile
        int ks2 = (u >> 8) & 3;  // hidden-k tile
        int r = u >> 10;
        int kbase = ks2 * 32 + (lane >> 4) * 8;
        int d = mt * 16 + (lane & 15);
        f16x8 v;
#pragma unroll
        for (int j = 0; j < 8; ++j)
            v[j] = (_Float16)rule_w2[((size_t)r * HD + kbase + j) * D + d];
        ((f16x8*)w2b)[((r * 4 + ks2) * 4 + mt) * 64 + lane] = v;
    }
}

// ---------------------------------------------------------------------------
// Evolve kernel R9: 64-token tile, 4 waves, rule-partitioned (R8 numerics).
// Structural changes vs R8:
//  - token-half x hcol-half phasing: per-rule H buffer 17.4KB -> 4.6KB
//    (32 tok x 64 hcol, stride 72 f16 = 144B, reused; GEMM2 split-K acc).
//  - cross-rule mix: ONE shared f32 arena + ds_add_f32 atomics (col
//    XOR-swizzled by (tok&7)<<2 to break stride-68 bank aliasing).
//  LDS = 9504 + 4*4608 + 17408 = 45344 B -> 3 blocks/CU.
// ---------------------------------------------------------------------------
__global__ __launch_bounds__(256, 3) void evolve_kernel(
    const float* __restrict__ src, float* __restrict__ dst,
    const float* __restrict__ ctrl,
    const _Float16* __restrict__ w1b, const _Float16* __restrict__ w2b,
    const float* __restrict__ b1, const float* __restrict__ b2, int iter)
{
    int n_evolve = (int)ctrl[5];
    if (iter >= n_evolve) return;

    float alpha = ctrl[4];
    float beta = 1.0f - alpha;

    __shared__ _Float16 cellsL[66 * 72];                   // 9504 B
    __shared__ __align__(16) _Float16 hq[4][32 * 72];      // 4 x 4608 B
    __shared__ __align__(16) float mix[64 * 68];           // 17408 B

    int blk = blockIdx.x;
    int b = blk >> 7;
    int t0 = (blk & 127) << 6;
    const float* srcb = src + (size_t)b * TT * D;

    int tid = threadIdx.x;
    // stage cells tile (fp32 -> f16 LDS, RNE casts)
    for (int idx = tid; idx < 66 * 16; idx += 256) {
        int row = idx >> 4;
        int c4 = (idx & 15) << 2;
        int tok = (t0 - 1 + row) & (TT - 1);
        f32x4 v = *(const f32x4*)(srcb + (size_t)tok * D + c4);
        *(f16x4*)&cellsL[row * 72 + c4] = cvt4_rne(v[0], v[1], v[2], v[3]);
    }
    // zero the mix arena (4352 f32 = 1088 f32x4)
    for (int idx = tid; idx < 1088; idx += 256)
        ((f32x4*)mix)[idx] = (f32x4){0.f, 0.f, 0.f, 0.f};
    __syncthreads();   // barrier 1

    int wave = tid >> 6;       // = rule index
    int lane = tid & 63;
    int lrow = lane & 15;
    int lgrp = lane >> 4;
    int r = wave;
    float rwr = ctrl[r];
    int swz = (lrow & 7) << 2;           // mix column XOR swizzle

    const f16x8* w1v = (const f16x8*)w1b;
    const f16x8* w2v = (const f16x8*)w2b;
    _Float16* hb = &hq[wave][0];

#pragma unroll
    for (int th = 0; th < 2; ++th) {
        // ---- A-fragments of X^T for this token-half (2 x 16 tokens)
        f16x8 af[2][6];
#pragma unroll
        for (int nt2 = 0; nt2 < 2; ++nt2) {
#pragma unroll
            for (int ks = 0; ks < 6; ++ks) {
                int k0 = ks * 32 + lgrp * 8;
                int seg = k0 >> 6;                 // 0:c[t] 1:c[t-1] 2:c[t+1]
                int kk = k0 & 63;
                int drow = (seg == 0) ? 1 : ((seg == 1) ? 0 : 2);
                af[nt2][ks] = *(const f16x8*)
                    &cellsL[(th * 32 + nt2 * 16 + lrow + drow) * 72 + kk];
            }
        }

        f32x4 acc2[4][2];   // split-K accumulator across hcol-halves
#pragma unroll
        for (int mt = 0; mt < 4; ++mt)
#pragma unroll
            for (int nt2 = 0; nt2 < 2; ++nt2)
                acc2[mt][nt2] = (f32x4){0.f, 0.f, 0.f, 0.f};

#pragma unroll
        for (int hh = 0; hh < 2; ++hh) {
            // ---- GEMM1 for hcols [hh*64, hh*64+64)
#pragma unroll
            for (int ht = 0; ht < 4; ++ht) {
                int htg = hh * 4 + ht;          // global hcol tile 0..7
                f32x4 acc1[2];
                acc1[0] = (f32x4){0.f, 0.f, 0.f, 0.f};
                acc1[1] = (f32x4){0.f, 0.f, 0.f, 0.f};
#pragma unroll
                for (int ks = 0; ks < 6; ++ks) {
                    f16x8 wf = w1v[(ks * 32 + r * 8 + htg) * 64 + lane];
                    acc1[0] = __builtin_amdgcn_mfma_f32_16x16x32_f16(wf, af[0][ks], acc1[0], 0, 0, 0);
                    acc1[1] = __builtin_amdgcn_mfma_f32_16x16x32_f16(wf, af[1][ks], acc1[1], 0, 0, 0);
                }
                f32x4 b1v = *(const f32x4*)&b1[r * HD + htg * 16 + lgrp * 4];
#pragma unroll
                for (int nt2 = 0; nt2 < 2; ++nt2) {
                    float g0 = gelu_tanh(acc1[nt2][0] + b1v[0]);
                    float g1 = gelu_tanh(acc1[nt2][1] + b1v[1]);
                    float g2 = gelu_tanh(acc1[nt2][2] + b1v[2]);
                    float g3 = gelu_tanh(acc1[nt2][3] + b1v[3]);
                    *(f16x4*)&hb[(nt2 * 16 + lrow) * 72 + ht * 16 + lgrp * 4]
                        = cvt4_rne(g0, g1, g2, g3);
                }
            }
            // ---- GEMM2 partial over this hcol-half (split-K)
#pragma unroll
            for (int ks2 = 0; ks2 < 2; ++ks2) {
                int ks2g = hh * 2 + ks2;
                f16x8 a2[2];
#pragma unroll
                for (int nt2 = 0; nt2 < 2; ++nt2)
                    a2[nt2] = *(const f16x8*)
                        &hb[(nt2 * 16 + lrow) * 72 + ks2 * 32 + lgrp * 8];
#pragma unroll
                for (int mt = 0; mt < 4; ++mt) {
                    f16x8 bw = w2v[((r * 4 + ks2g) * 4 + mt) * 64 + lane];
                    acc2[mt][0] = __builtin_amdgcn_mfma_f32_16x16x32_f16(bw, a2[0], acc2[mt][0], 0, 0, 0);
                    acc2[mt][1] = __builtin_amdgcn_mfma_f32_16x16x32_f16(bw, a2[1], acc2[mt][1], 0, 0, 0);
                }
            }
        }

        // ---- tanh * rule_weight -> atomic add into the shared mix arena
#pragma unroll
        for (int mt = 0; mt < 4; ++mt) {
            f32x4 b2v = *(const f32x4*)&b2[r * D + mt * 16 + lgrp * 4];
#pragma unroll
            for (int nt2 = 0; nt2 < 2; ++nt2) {
                int tokl = th * 32 + nt2 * 16 + lrow;
                int colbase = (mt * 16 + lgrp * 4) ^ swz;   // bits 0-1 clear
#pragma unroll
                for (int q = 0; q < 4; ++q) {
                    float v = rwr * fast_tanh(acc2[mt][nt2][q] + b2v[q]);
                    atomicAdd(&mix[tokl * 68 + colbase + q], v);
                }
            }
        }
    }

    __syncthreads();   // barrier 2

    // ---- alpha mix + store; thread -> (token, d-quarter), swizzled reads
    int tok = tid >> 2;                 // 0..63
    int dq = tid & 3;                   // d-quarter
    int rswz = (tok & 7) << 2;
    size_t roff = (size_t)b * TT * D + (size_t)(t0 + tok) * D + dq * 16;
#pragma unroll
    for (int j = 0; j < 4; ++j) {
        int col = (dq * 16 + j * 4) ^ rswz;
        f32x4 m = *(const f32x4*)&mix[tok * 68 + col];
        f32x4 s = *(const f32x4*)(src + roff + j * 4);
        f32x4 o;
#pragma unroll
        for (int q = 0; q < 4; ++q)
            o[q] = alpha * s[q] + beta * m[q];
        *(f32x4*)(dst + roff + j * 4) = o;
    }
}

// ---------------------------------------------------------------------------
// LayerNorm kernel: 16 lanes per row, float4 per lane. Parity-select source.
// ---------------------------------------------------------------------------
__global__ __launch_bounds__(256) void ln_kernel(
    const float* __restrict__ ctrl, const float* __restrict__ bufA,
    const float* __restrict__ bufB, const float* __restrict__ g,
    const float* __restrict__ bvec, float* __restrict__ out)
{
    int n = (int)ctrl[5];
    const float* src = (n & 1) ? bufB : bufA;
    int lane = threadIdx.x & 63;
    int gw = (blockIdx.x * 256 + threadIdx.x) >> 6;
    int nw = (gridDim.x * 256) >> 6;
    int r4 = lane >> 4;
    int c0 = (lane & 15) << 2;
    float4 gv = *(const float4*)(g + c0);
    float4 bv = *(const float4*)(bvec + c0);
    const int totalRowBlk = (BBATCH * TT) / 4;
    for (int rb = gw; rb < totalRowBlk; rb += nw) {
        size_t row = (size_t)rb * 4 + r4;
        float4 v = *(const float4*)(src + row * D + c0);
        float s = v.x + v.y + v.z + v.w;
        float s2 = v.x * v.x + v.y * v.y + v.z * v.z + v.w * v.w;
#pragma unroll
        for (int m = 1; m < 16; m <<= 1) {
            s  += __shfl_xor(s, m, 64);
            s2 += __shfl_xor(s2, m, 64);
        }
        float mu = s * (1.0f / 64.0f);
        float inv = rsqrtf(s2 * (1.0f / 64.0f) - mu * mu + 1e-5f);
        float4 o;
        o.x = (v.x - mu) * inv * gv.x + bv.x;
        o.y = (v.y - mu) * inv * gv.y + bv.y;
        o.z = (v.z - mu) * inv * gv.z + bv.z;
        o.w = (v.w - mu) * inv * gv.w + bv.w;
        *(float4*)(out + row * D + c0) = o;
    }
}

// ---------------------------------------------------------------------------
extern "C" void kernel_launch(void* const* d_in, const int* in_sizes, int n_in,
                              void* d_out, int out_size, void* d_ws, size_t ws_size,
                              hipStream_t stream) {
    const float* cells   = (const float*)d_in[0];
    const float* c_state = (const float*)d_in[1];
    const float* rule_w1 = (const float*)d_in[2];
    const float* rule_b1 = (const float*)d_in[3];
    const float* rule_w2 = (const float*)d_in[4];
    const float* rule_b2 = (const float*)d_in[5];
    const float* sel_w1  = (const float*)d_in[6];
    const float* sel_b1  = (const float*)d_in[7];
    const float* sel_w2  = (const float*)d_in[8];
    const float* sel_b2  = (const float*)d_in[9];
    const float* st_w1   = (const float*)d_in[10];
    const float* st_b1   = (const float*)d_in[11];
    const float* st_w2   = (const float*)d_in[12];
    const float* st_b2   = (const float*)d_in[13];
    const float* res_w1  = (const float*)d_in[14];
    const float* res_b1  = (const float*)d_in[15];
    const float* res_w2  = (const float*)d_in[16];
    const float* res_b2  = (const float*)d_in[17];
    const float* ln_g    = (const float*)d_in[18];
    const float* ln_b    = (const float*)d_in[19];

    float* out = (float*)d_out;
    char* ws = (char*)d_ws;
    float* ctrl = (float*)ws;                              // 64 B
    _Float16* w1b = (_Float16*)(ws + 256);                 // 196608 B
    _Float16* w2b = (_Float16*)(ws + 256 + 196608);        // 65536 B
    float* bufA = (float*)(ws + (512u * 1024u));           // 64 MiB ping buffer

    control_kernel<<<1, 64, 0, stream>>>(c_state,
        sel_w1, sel_b1, sel_w2, sel_b2,
        st_w1, st_b1, st_w2, st_b2,
        res_w1, res_b1, res_w2, res_b2, ctrl);

    prep_kernel<<<64, 256, 0, stream>>>(rule_w1, rule_w2, w1b, w2b);

    // ping-pong: dst of even iter = d_out, of odd iter = bufA.
    for (int i = 0; i < 8; ++i) {
        const float* s = (i == 0) ? cells : ((i & 1) ? out : bufA);
        float* dptr = (i & 1) ? bufA : out;
        evolve_kernel<<<4096, 256, 0, stream>>>(s, dptr, ctrl, w1b, w2b,
                                                rule_b1, rule_b2, i);
    }

    // final cells in d_out if n_evolve odd, in bufA if even; LN picks by parity
    ln_kernel<<<2048, 256, 0, stream>>>(ctrl, bufA, out, ln_g, ln_b, out);
}

// Round 10
// 1799.475 us; speedup vs baseline: 1.2095x; 1.2095x over previous
//
#include <hip/hip_runtime.h>
#include <hip/hip_cooperative_groups.h>
#include <cmath>

namespace cg = cooperative_groups;

#define D 64
#define HD 128
#define K1 192
#define TT 8192
#define BBATCH 32
#define RULES 4

typedef _Float16 f16x8 __attribute__((ext_vector_type(8)));
typedef _Float16 f16x4 __attribute__((ext_vector_type(4)));
typedef float f32x4 __attribute__((ext_vector_type(4)));

__device__ __forceinline__ float gelu_exact(float x) {
    return 0.5f * x * (1.0f + erff(x * 0.70710678118654752f));
}

__device__ __forceinline__ float fast_rcp(float x) { return __builtin_amdgcn_rcpf(x); }
__device__ __forceinline__ float fast_exp2(float x) { return __builtin_amdgcn_exp2f(x); }

// tanh-approx GELU (R8, passing): ~6 VALU + 2 trans.
__device__ __forceinline__ float gelu_tanh(float x) {
    float x2 = x * x;
    float t = x * fmaf(x2, -0.10294443f, -2.30220820f);
    return x * fast_rcp(1.0f + fast_exp2(t));
}
// tanh(x) = 1 - 2/(exp2(2*log2e*x)+1) ; exact identity, saturates cleanly
__device__ __forceinline__ float fast_tanh(float x) {
    float e = fast_exp2(x * 2.8853900817779268f);
    return 1.0f - 2.0f * fast_rcp(e + 1.0f);
}

__device__ __forceinline__ f16x4 cvt4_rne(float a, float b, float c, float d) {
    f16x4 r;
    r[0] = (_Float16)a; r[1] = (_Float16)b;
    r[2] = (_Float16)c; r[3] = (_Float16)d;
    return r;
}

// ---------------------------------------------------------------------------
// Control kernel: rule_weights[4], alpha, n_evolve  -> ctrl[0..5]
// ---------------------------------------------------------------------------
__global__ void control_kernel(
    const float* __restrict__ c_state,
    const float* __restrict__ sel_w1, const float* __restrict__ sel_b1,
    const float* __restrict__ sel_w2, const float* __restrict__ sel_b2,
    const float* __restrict__ st_w1,  const float* __restrict__ st_b1,
    const float* __restrict__ st_w2,  const float* __restrict__ st_b2,
    const float* __restrict__ res_w1, const float* __restrict__ res_b1,
    const float* __restrict__ res_w2, const float* __restrict__ res_b2,
    float* __restrict__ ctrl)
{
    __shared__ float cs[128];
    __shared__ float h1s[64], h2s[32], h3s[32];
    __shared__ float lg[12];
    int l = threadIdx.x;  // 64 threads
    cs[l] = c_state[l];
    cs[l + 64] = c_state[l + 64];
    __syncthreads();
    {
        float a = sel_b1[l];
        for (int k = 0; k < 128; ++k) a += cs[k] * sel_w1[k * 64 + l];
        h1s[l] = gelu_exact(a);
    }
    if (l < 32) {
        float a = st_b1[l];
        for (int k = 0; k < 128; ++k) a += cs[k] * st_w1[k * 32 + l];
        h2s[l] = gelu_exact(a);
        float a2 = res_b1[l];
        for (int k = 0; k < 128; ++k) a2 += cs[k] * res_w1[k * 32 + l];
        h3s[l] = gelu_exact(a2);
    }
    __syncthreads();
    if (l < 4) {
        float a = sel_b2[l];
        for (int j = 0; j < 64; ++j) a += h1s[j] * sel_w2[j * 4 + l];
        lg[l] = a;
    }
    if (l >= 8 && l < 15) {
        int s = l - 8;
        float a = st_b2[s];
        for (int j = 0; j < 32; ++j) a += h2s[j] * st_w2[j * 7 + s];
        lg[4 + s] = a;
    }
    if (l == 32) {
        float a = res_b2[0];
        for (int j = 0; j < 32; ++j) a += h3s[j] * res_w2[j];
        lg[11] = a;
    }
    __syncthreads();
    if (l == 0) {
        float m = fmaxf(fmaxf(lg[0], lg[1]), fmaxf(lg[2], lg[3]));
        float e0 = expf(lg[0] - m), e1 = expf(lg[1] - m);
        float e2 = expf(lg[2] - m), e3 = expf(lg[3] - m);
        float s = e0 + e1 + e2 + e3;
        ctrl[0] = e0 / s; ctrl[1] = e1 / s; ctrl[2] = e2 / s; ctrl[3] = e3 / s;
        float m2 = lg[4];
        for (int i = 1; i < 7; ++i) m2 = fmaxf(m2, lg[4 + i]);
        float ss = 0.f, es[7];
        for (int i = 0; i < 7; ++i) { es[i] = expf(lg[4 + i] - m2); ss += es[i]; }
        float nsoft = 0.f;
        for (int i = 0; i < 7; ++i) nsoft += (es[i] / ss) * (float)(i + 2);
        int n = (int)(nsoft + 0.5f);
        n = n < 2 ? 2 : (n > 8 ? 8 : n);
        float alpha = 0.1f + 0.8f / (1.0f + expf(-lg[11]));
        ctrl[4] = alpha;
        ctrl[5] = (float)n;
    }
}

// ---------------------------------------------------------------------------
// Prep kernel (unchanged layouts — verified R4-R9):
//   w1b: A-fragments of W1^T  [ks(6)][htile(32, = r*8+ht)][lane][8]
//   w2b: A-fragments of W2^T  [r][ks2][dtile(4)][lane][8]
// ---------------------------------------------------------------------------
__global__ __launch_bounds__(256) void prep_kernel(
    const float* __restrict__ rule_w1, const float* __restrict__ rule_w2,
    _Float16* __restrict__ w1b, _Float16* __restrict__ w2b)
{
    int t = blockIdx.x * 256 + threadIdx.x;
    if (t < 12288) {
        int lane = t & 63;
        int x = t >> 6;          // 0..191
        int htile = x & 31;      // global h tile (r = htile>>3)
        int ks = x >> 5;         // 0..5
        int r = htile >> 3;
        int h128 = (htile & 7) * 16 + (lane & 15);
        int kbase = ks * 32 + (lane >> 4) * 8;
        f16x8 v;
#pragma unroll
        for (int j = 0; j < 8; ++j)
            v[j] = (_Float16)rule_w1[((size_t)r * K1 + kbase + j) * HD + h128];
        ((f16x8*)w1b)[(ks * 32 + htile) * 64 + lane] = v;
    } else if (t < 12288 + 4096) {
        int u = t - 12288;
        int lane = u & 63;
        int mt = (u >> 6) & 3;   // d tile
        int ks2 = (u >> 8) & 3;  // hidden-k tile
        int r = u >> 10;
        int kbase = ks2 * 32 + (lane >> 4) * 8;
        int d = mt * 16 + (lane & 15);
        f16x8 v;
#pragma unroll
        for (int j = 0; j < 8; ++j)
            v[j] = (_Float16)rule_w2[((size_t)r * HD + kbase + j) * D + d];
        ((f16x8*)w2b)[((r * 4 + ks2) * 4 + mt) * 64 + lane] = v;
    }
}

// ---------------------------------------------------------------------------
// Device-side tile body (identical math/layout to R8's evolve_kernel).
// Processes one 64-token tile for one iteration. If `last`, applies fused
// LayerNorm and writes `fin`; otherwise writes alpha-mixed cells to `dst`.
// ---------------------------------------------------------------------------
__device__ __forceinline__ void evolve_tile(
    int tile, const float* __restrict__ src, float* __restrict__ dst,
    const _Float16* __restrict__ w1b, const _Float16* __restrict__ w2b,
    const float* __restrict__ b1, const float* __restrict__ b2,
    const float* __restrict__ ln_g, const float* __restrict__ ln_b,
    float* __restrict__ fin, bool last, float alpha, float beta, float rwr,
    _Float16* cellsL, _Float16 (*arena)[64 * 136])
{
    int b = tile >> 7;
    int t0 = (tile & 127) << 6;
    const float* srcb = src + (size_t)b * TT * D;

    int tid = threadIdx.x;
    // stage cells tile (fp32 -> f16 LDS, RNE casts)
    for (int idx = tid; idx < 66 * 16; idx += 256) {
        int row = idx >> 4;
        int c4 = (idx & 15) << 2;
        int tok = (t0 - 1 + row) & (TT - 1);
        f32x4 v = *(const f32x4*)(srcb + (size_t)tok * D + c4);
        *(f16x4*)&cellsL[row * 72 + c4] = cvt4_rne(v[0], v[1], v[2], v[3]);
    }
    __syncthreads();   // barrier 1 (also protects arena reuse across tiles)

    int wave = tid >> 6;       // = rule index
    int lane = tid & 63;
    int lrow = lane & 15;
    int lgrp = lane >> 4;
    int r = wave;

    const f16x8* w1v = (const f16x8*)w1b;
    const f16x8* w2v = (const f16x8*)w2b;
    _Float16* hb = &arena[wave][0];

    // ---- GEMM1: h^T = W1_r^T X^T  (128 hcols x 64 tokens)
    f32x4 acc1[8][4];
#pragma unroll
    for (int ht = 0; ht < 8; ++ht)
#pragma unroll
        for (int nt = 0; nt < 4; ++nt)
            acc1[ht][nt] = (f32x4){0.f, 0.f, 0.f, 0.f};

#pragma unroll
    for (int ks = 0; ks < 6; ++ks) {
        int k0 = ks * 32 + lgrp * 8;
        int seg = k0 >> 6;                     // 0:c[t] 1:c[t-1] 2:c[t+1]
        int kk = k0 & 63;
        int drow = (seg == 0) ? 1 : ((seg == 1) ? 0 : 2);
        f16x8 a_[4];
#pragma unroll
        for (int nt = 0; nt < 4; ++nt)
            a_[nt] = *(const f16x8*)&cellsL[(nt * 16 + lrow + drow) * 72 + kk];
#pragma unroll
        for (int ht = 0; ht < 8; ++ht) {
            f16x8 wf = w1v[(ks * 32 + r * 8 + ht) * 64 + lane];
#pragma unroll
            for (int nt = 0; nt < 4; ++nt)
                acc1[ht][nt] = __builtin_amdgcn_mfma_f32_16x16x32_f16(wf, a_[nt], acc1[ht][nt], 0, 0, 0);
        }
    }

    // gelu + wave-private H store (no barrier: same-wave LDS dependency)
#pragma unroll
    for (int ht = 0; ht < 8; ++ht) {
        f32x4 b1v = *(const f32x4*)&b1[r * HD + ht * 16 + lgrp * 4];
#pragma unroll
        for (int nt = 0; nt < 4; ++nt) {
            float g0 = gelu_tanh(acc1[ht][nt][0] + b1v[0]);
            float g1 = gelu_tanh(acc1[ht][nt][1] + b1v[1]);
            float g2 = gelu_tanh(acc1[ht][nt][2] + b1v[2]);
            float g3 = gelu_tanh(acc1[ht][nt][3] + b1v[3]);
            *(f16x4*)&hb[(nt * 16 + lrow) * 136 + ht * 16 + lgrp * 4]
                = cvt4_rne(g0, g1, g2, g3);
        }
    }

    // ---- GEMM2: out^T = W2_r^T H^T  (64 d x 64 tokens), wave-private
    f32x4 acc2[4][4];
#pragma unroll
    for (int mt = 0; mt < 4; ++mt)
#pragma unroll
        for (int nt = 0; nt < 4; ++nt)
            acc2[mt][nt] = (f32x4){0.f, 0.f, 0.f, 0.f};

#pragma unroll
    for (int ks2 = 0; ks2 < 4; ++ks2) {
        f16x8 a2[4];
#pragma unroll
        for (int nt = 0; nt < 4; ++nt)
            a2[nt] = *(const f16x8*)&hb[(nt * 16 + lrow) * 136 + ks2 * 32 + lgrp * 8];
#pragma unroll
        for (int mt = 0; mt < 4; ++mt) {
            f16x8 bw = w2v[((r * 4 + ks2) * 4 + mt) * 64 + lane];
#pragma unroll
            for (int nt = 0; nt < 4; ++nt)
                acc2[mt][nt] = __builtin_amdgcn_mfma_f32_16x16x32_f16(bw, a2[nt], acc2[mt][nt], 0, 0, 0);
        }
    }

    // tanh * rule_weight -> f32 mix slice in the SAME arena (H is dead now)
    float* mixw = (float*)hb;   // [64 tokens][stride 68 f32]
#pragma unroll
    for (int mt = 0; mt < 4; ++mt) {
        f32x4 b2v = *(const f32x4*)&b2[r * D + mt * 16 + lgrp * 4];
#pragma unroll
        for (int nt = 0; nt < 4; ++nt) {
            f32x4 o;
#pragma unroll
            for (int q = 0; q < 4; ++q)
                o[q] = rwr * fast_tanh(acc2[mt][nt][q] + b2v[q]);
            *(f32x4*)&mixw[(nt * 16 + lrow) * 68 + mt * 16 + lgrp * 4] = o;
        }
    }

    __syncthreads();   // barrier 2

    // ---- cross-rule reduce + alpha mix; thread -> (token, d-quarter)
    int tok = tid >> 2;                 // 0..63
    int dq = tid & 3;                   // d-quarter (16 contiguous d)
    const float* ar0 = (const float*)&arena[0][0];
    const float* ar1 = (const float*)&arena[1][0];
    const float* ar2 = (const float*)&arena[2][0];
    const float* ar3 = (const float*)&arena[3][0];
    int mbase = tok * 68 + dq * 16;
    size_t roff = (size_t)b * TT * D + (size_t)(t0 + tok) * D + dq * 16;

    f32x4 ov[4];
    float m0 = 0.f, m1 = 0.f;
#pragma unroll
    for (int j = 0; j < 4; ++j) {
        f32x4 v0 = *(const f32x4*)(ar0 + mbase + j * 4);
        f32x4 v1 = *(const f32x4*)(ar1 + mbase + j * 4);
        f32x4 v2 = *(const f32x4*)(ar2 + mbase + j * 4);
        f32x4 v3 = *(const f32x4*)(ar3 + mbase + j * 4);
        f32x4 s  = *(const f32x4*)(src + roff + j * 4);
#pragma unroll
        for (int q = 0; q < 4; ++q) {
            float v = alpha * s[q] + beta * (v0[q] + v1[q] + v2[q] + v3[q]);
            ov[j][q] = v; m0 += v; m1 += v * v;
        }
    }

    if (!last) {
#pragma unroll
        for (int j = 0; j < 4; ++j)
            *(f32x4*)(dst + roff + j * 4) = ov[j];
    } else {
        // fused LayerNorm: token's 64 d live in 4 consecutive lanes (dq 0-3)
        m0 += __shfl_xor(m0, 1, 64); m1 += __shfl_xor(m1, 1, 64);
        m0 += __shfl_xor(m0, 2, 64); m1 += __shfl_xor(m1, 2, 64);
        float mu = m0 * (1.0f / 64.0f);
        float inv = rsqrtf(m1 * (1.0f / 64.0f) - mu * mu + 1e-5f);
#pragma unroll
        for (int j = 0; j < 4; ++j) {
            f32x4 g4 = *(const f32x4*)&ln_g[dq * 16 + j * 4];
            f32x4 b4 = *(const f32x4*)&ln_b[dq * 16 + j * 4];
            f32x4 o;
#pragma unroll
            for (int q = 0; q < 4; ++q)
                o[q] = (ov[j][q] - mu) * inv * g4[q] + b4[q];
            *(f32x4*)(fin + roff + j * 4) = o;
        }
    }
}

// ---------------------------------------------------------------------------
// Cooperative megakernel: all n_evolve iterations + fused LN in one launch.
// Grid-strided tiles; grid.sync() between iterations. Buffer parity chosen
// backwards from n so the FINAL iteration always reads bufA (never aliases
// the LN output buffer `out`).
// ---------------------------------------------------------------------------
__global__ __launch_bounds__(256, 2) void mega_kernel(
    const float* __restrict__ cells, const float* __restrict__ ctrl,
    const _Float16* __restrict__ w1b, const _Float16* __restrict__ w2b,
    const float* __restrict__ b1, const float* __restrict__ b2,
    const float* __restrict__ ln_g, const float* __restrict__ ln_b,
    float* __restrict__ out, float* __restrict__ bufA)
{
    cg::grid_group gg = cg::this_grid();

    __shared__ _Float16 cellsL[66 * 72];                     // 9504 B
    __shared__ __align__(16) _Float16 arena[4][64 * 136];    // 4 x 17408 B

    int n = (int)ctrl[5];          // in [2,8]
    float alpha = ctrl[4];
    float beta = 1.0f - alpha;
    float rwr = ctrl[threadIdx.x >> 6];

    for (int it = 0; it < n; ++it) {
        bool last = (it == n - 1);
        // dst of iter i (i<n-1): bufA if (n-2-i) even else out  => iter n-2
        // always writes bufA, so the last iteration's src is always bufA.
        const float* src = (it == 0) ? cells
                           : ((((n - 1 - it) & 1) == 0) ? bufA : out);
        float* dst = (((n - 2 - it) & 1) == 0) ? bufA : out;   // unused if last

        for (int tile = blockIdx.x; tile < BBATCH * (TT / 64); tile += gridDim.x)
            evolve_tile(tile, src, dst, w1b, w2b, b1, b2, ln_g, ln_b,
                        out, last, alpha, beta, rwr, cellsL, arena);

        if (!last) {
            __threadfence();
            gg.sync();
        }
    }
}

// ---------------------------------------------------------------------------
// Fallback kernels (R8 scheme) in case cooperative launch is unavailable.
// ---------------------------------------------------------------------------
__global__ __launch_bounds__(256, 2) void evolve_kernel(
    const float* __restrict__ src, float* __restrict__ dst,
    const float* __restrict__ ctrl,
    const _Float16* __restrict__ w1b, const _Float16* __restrict__ w2b,
    const float* __restrict__ b1, const float* __restrict__ b2, int iter)
{
    int n_evolve = (int)ctrl[5];
    if (iter >= n_evolve) return;
    __shared__ _Float16 cellsL[66 * 72];
    __shared__ __align__(16) _Float16 arena[4][64 * 136];
    float alpha = ctrl[4];
    float rwr = ctrl[threadIdx.x >> 6];
    evolve_tile(blockIdx.x, src, dst, w1b, w2b, b1, b2, nullptr, nullptr,
                nullptr, false, alpha, 1.0f - alpha, rwr, cellsL, arena);
}

__global__ __launch_bounds__(256) void ln_kernel(
    const float* __restrict__ ctrl, const float* __restrict__ bufA,
    const float* __restrict__ bufB, const float* __restrict__ g,
    const float* __restrict__ bvec, float* __restrict__ out)
{
    int n = (int)ctrl[5];
    const float* src = (n & 1) ? bufB : bufA;
    int lane = threadIdx.x & 63;
    int gw = (blockIdx.x * 256 + threadIdx.x) >> 6;
    int nw = (gridDim.x * 256) >> 6;
    int r4 = lane >> 4;
    int c0 = (lane & 15) << 2;
    float4 gv = *(const float4*)(g + c0);
    float4 bv = *(const float4*)(bvec + c0);
    const int totalRowBlk = (BBATCH * TT) / 4;
    for (int rb = gw; rb < totalRowBlk; rb += nw) {
        size_t row = (size_t)rb * 4 + r4;
        float4 v = *(const float4*)(src + row * D + c0);
        float s = v.x + v.y + v.z + v.w;
        float s2 = v.x * v.x + v.y * v.y + v.z * v.z + v.w * v.w;
#pragma unroll
        for (int m = 1; m < 16; m <<= 1) {
            s  += __shfl_xor(s, m, 64);
            s2 += __shfl_xor(s2, m, 64);
        }
        float mu = s * (1.0f / 64.0f);
        float inv = rsqrtf(s2 * (1.0f / 64.0f) - mu * mu + 1e-5f);
        float4 o;
        o.x = (v.x - mu) * inv * gv.x + bv.x;
        o.y = (v.y - mu) * inv * gv.y + bv.y;
        o.z = (v.z - mu) * inv * gv.z + bv.z;
        o.w = (v.w - mu) * inv * gv.w + bv.w;
        *(float4*)(out + row * D + c0) = o;
    }
}

// ---------------------------------------------------------------------------
extern "C" void kernel_launch(void* const* d_in, const int* in_sizes, int n_in,
                              void* d_out, int out_size, void* d_ws, size_t ws_size,
                              hipStream_t stream) {
    const float* cells   = (const float*)d_in[0];
    const float* c_state = (const float*)d_in[1];
    const float* rule_w1 = (const float*)d_in[2];
    const float* rule_b1 = (const float*)d_in[3];
    const float* rule_w2 = (const float*)d_in[4];
    const float* rule_b2 = (const float*)d_in[5];
    const float* sel_w1  = (const float*)d_in[6];
    const float* sel_b1  = (const float*)d_in[7];
    const float* sel_w2  = (const float*)d_in[8];
    const float* sel_b2  = (const float*)d_in[9];
    const float* st_w1   = (const float*)d_in[10];
    const float* st_b1   = (const float*)d_in[11];
    const float* st_w2   = (const float*)d_in[12];
    const float* st_b2   = (const float*)d_in[13];
    const float* res_w1  = (const float*)d_in[14];
    const float* res_b1  = (const float*)d_in[15];
    const float* res_w2  = (const float*)d_in[16];
    const float* res_b2  = (const float*)d_in[17];
    const float* ln_g    = (const float*)d_in[18];
    const float* ln_b    = (const float*)d_in[19];

    float* out = (float*)d_out;
    char* ws = (char*)d_ws;
    float* ctrl = (float*)ws;                              // 64 B
    _Float16* w1b = (_Float16*)(ws + 256);                 // 196608 B
    _Float16* w2b = (_Float16*)(ws + 256 + 196608);        // 65536 B
    float* bufA = (float*)(ws + (512u * 1024u));           // 64 MiB ping buffer

    control_kernel<<<1, 64, 0, stream>>>(c_state,
        sel_w1, sel_b1, sel_w2, sel_b2,
        st_w1, st_b1, st_w2, st_b2,
        res_w1, res_b1, res_w2, res_b2, ctrl);

    prep_kernel<<<64, 256, 0, stream>>>(rule_w1, rule_w2, w1b, w2b);

    // ---- cooperative megakernel (all iterations + fused LN) ----
    int dev = 0;
    hipGetDevice(&dev);
    int cus = 0;
    hipDeviceGetAttribute(&cus, hipDeviceAttributeMultiprocessorCount, dev);
    int perCU = 0;
    hipOccupancyMaxActiveBlocksPerMultiprocessor(&perCU, mega_kernel, 256, 0);

    hipError_t rc = hipErrorUnknown;
    if (cus > 0 && perCU > 0) {
        int grid = perCU * cus;
        if (grid > BBATCH * (TT / 64)) grid = BBATCH * (TT / 64);
        void* args[] = { (void*)&cells, (void*)&ctrl, (void*)&w1b, (void*)&w2b,
                         (void*)&rule_b1, (void*)&rule_b2, (void*)&ln_g,
                         (void*)&ln_b, (void*)&out, (void*)&bufA };
        rc = hipLaunchCooperativeKernel((void*)mega_kernel, dim3(grid),
                                        dim3(256), args, 0, stream);
    }

    if (rc != hipSuccess) {
        // Fallback: R8 launch scheme (8 evolve launches + parity LN)
        for (int i = 0; i < 8; ++i) {
            const float* s = (i == 0) ? cells : ((i & 1) ? out : bufA);
            float* dptr = (i & 1) ? bufA : out;
            evolve_kernel<<<4096, 256, 0, stream>>>(s, dptr, ctrl, w1b, w2b,
                                                    rule_b1, rule_b2, i);
        }
        ln_kernel<<<2048, 256, 0, stream>>>(ctrl, bufA, out, ln_g, ln_b, out);
    }
}

// Round 11
// 593.512 us; speedup vs baseline: 3.6671x; 3.0319x over previous
//
#include <hip/hip_runtime.h>
#include <cmath>

#define D 64
#define HD 128
#define K1 192
#define TT 8192
#define BBATCH 32
#define RULES 4

typedef _Float16 f16x8 __attribute__((ext_vector_type(8)));
typedef _Float16 f16x4 __attribute__((ext_vector_type(4)));
typedef float f32x4 __attribute__((ext_vector_type(4)));

__device__ __forceinline__ float gelu_exact(float x) {
    return 0.5f * x * (1.0f + erff(x * 0.70710678118654752f));
}

__device__ __forceinline__ float fast_rcp(float x) { return __builtin_amdgcn_rcpf(x); }
__device__ __forceinline__ float fast_exp2(float x) { return __builtin_amdgcn_exp2f(x); }

// tanh-approx GELU (R8, passing): ~6 VALU + 2 trans.
__device__ __forceinline__ float gelu_tanh(float x) {
    float x2 = x * x;
    float t = x * fmaf(x2, -0.10294443f, -2.30220820f);
    return x * fast_rcp(1.0f + fast_exp2(t));
}
// tanh(x) = 1 - 2/(exp2(2*log2e*x)+1) ; exact identity, saturates cleanly
__device__ __forceinline__ float fast_tanh(float x) {
    float e = fast_exp2(x * 2.8853900817779268f);
    return 1.0f - 2.0f * fast_rcp(e + 1.0f);
}

__device__ __forceinline__ f16x4 cvt4_rne(float a, float b, float c, float d) {
    f16x4 r;
    r[0] = (_Float16)a; r[1] = (_Float16)b;
    r[2] = (_Float16)c; r[3] = (_Float16)d;
    return r;
}

// ---------------------------------------------------------------------------
// Prep+control kernel: blocks 0..63 re-layout weights (verified R4-R10);
// block 64 computes rule_weights[4], alpha, n_evolve -> ctrl[0..5].
//   w1b: A-fragments of W1^T  [ks(6)][htile(32, = r*8+ht)][lane][8]
//   w2b: A-fragments of W2^T  [r][ks2][dtile(4)][lane][8]
// ---------------------------------------------------------------------------
__global__ __launch_bounds__(256) void prep_control_kernel(
    const float* __restrict__ rule_w1, const float* __restrict__ rule_w2,
    _Float16* __restrict__ w1b, _Float16* __restrict__ w2b,
    const float* __restrict__ c_state,
    const float* __restrict__ sel_w1, const float* __restrict__ sel_b1,
    const float* __restrict__ sel_w2, const float* __restrict__ sel_b2,
    const float* __restrict__ st_w1,  const float* __restrict__ st_b1,
    const float* __restrict__ st_w2,  const float* __restrict__ st_b2,
    const float* __restrict__ res_w1, const float* __restrict__ res_b1,
    const float* __restrict__ res_w2, const float* __restrict__ res_b2,
    float* __restrict__ ctrl)
{
    if (blockIdx.x < 64) {
        int t = blockIdx.x * 256 + threadIdx.x;
        if (t < 12288) {
            int lane = t & 63;
            int x = t >> 6;          // 0..191
            int htile = x & 31;      // global h tile (r = htile>>3)
            int ks = x >> 5;         // 0..5
            int r = htile >> 3;
            int h128 = (htile & 7) * 16 + (lane & 15);
            int kbase = ks * 32 + (lane >> 4) * 8;
            f16x8 v;
#pragma unroll
            for (int j = 0; j < 8; ++j)
                v[j] = (_Float16)rule_w1[((size_t)r * K1 + kbase + j) * HD + h128];
            ((f16x8*)w1b)[(ks * 32 + htile) * 64 + lane] = v;
        } else if (t < 12288 + 4096) {
            int u = t - 12288;
            int lane = u & 63;
            int mt = (u >> 6) & 3;   // d tile
            int ks2 = (u >> 8) & 3;  // hidden-k tile
            int r = u >> 10;
            int kbase = ks2 * 32 + (lane >> 4) * 8;
            int d = mt * 16 + (lane & 15);
            f16x8 v;
#pragma unroll
            for (int j = 0; j < 8; ++j)
                v[j] = (_Float16)rule_w2[((size_t)r * HD + kbase + j) * D + d];
            ((f16x8*)w2b)[((r * 4 + ks2) * 4 + mt) * 64 + lane] = v;
        }
        return;
    }

    // ---- control block (blockIdx.x == 64); all 256 threads hit barriers
    __shared__ float cs[128];
    __shared__ float h1s[64], h2s[32], h3s[32];
    __shared__ float lg[12];
    int l = threadIdx.x;
    if (l < 64) { cs[l] = c_state[l]; cs[l + 64] = c_state[l + 64]; }
    __syncthreads();
    if (l < 64) {
        float a = sel_b1[l];
        for (int k = 0; k < 128; ++k) a += cs[k] * sel_w1[k * 64 + l];
        h1s[l] = gelu_exact(a);
    }
    if (l < 32) {
        float a = st_b1[l];
        for (int k = 0; k < 128; ++k) a += cs[k] * st_w1[k * 32 + l];
        h2s[l] = gelu_exact(a);
        float a2 = res_b1[l];
        for (int k = 0; k < 128; ++k) a2 += cs[k] * res_w1[k * 32 + l];
        h3s[l] = gelu_exact(a2);
    }
    __syncthreads();
    if (l < 4) {
        float a = sel_b2[l];
        for (int j = 0; j < 64; ++j) a += h1s[j] * sel_w2[j * 4 + l];
        lg[l] = a;
    }
    if (l >= 8 && l < 15) {
        int s = l - 8;
        float a = st_b2[s];
        for (int j = 0; j < 32; ++j) a += h2s[j] * st_w2[j * 7 + s];
        lg[4 + s] = a;
    }
    if (l == 32) {
        float a = res_b2[0];
        for (int j = 0; j < 32; ++j) a += h3s[j] * res_w2[j];
        lg[11] = a;
    }
    __syncthreads();
    if (l == 0) {
        float m = fmaxf(fmaxf(lg[0], lg[1]), fmaxf(lg[2], lg[3]));
        float e0 = expf(lg[0] - m), e1 = expf(lg[1] - m);
        float e2 = expf(lg[2] - m), e3 = expf(lg[3] - m);
        float s = e0 + e1 + e2 + e3;
        ctrl[0] = e0 / s; ctrl[1] = e1 / s; ctrl[2] = e2 / s; ctrl[3] = e3 / s;
        float m2 = lg[4];
        for (int i = 1; i < 7; ++i) m2 = fmaxf(m2, lg[4 + i]);
        float ss = 0.f, es[7];
        for (int i = 0; i < 7; ++i) { es[i] = expf(lg[4 + i] - m2); ss += es[i]; }
        float nsoft = 0.f;
        for (int i = 0; i < 7; ++i) nsoft += (es[i] / ss) * (float)(i + 2);
        int n = (int)(nsoft + 0.5f);
        n = n < 2 ? 2 : (n > 8 ? 8 : n);
        float alpha = 0.1f + 0.8f / (1.0f + expf(-lg[11]));
        ctrl[4] = alpha;
        ctrl[5] = (float)n;
    }
}

// ---------------------------------------------------------------------------
// Device-side tile body (identical math/layout to R8; LN path verified R10).
// Processes one 64-token tile for one iteration. If `last`, applies fused
// LayerNorm and writes `fin`; otherwise writes alpha-mixed cells to `dst`.
// ---------------------------------------------------------------------------
__device__ __forceinline__ void evolve_tile(
    int tile, const float* __restrict__ src, float* __restrict__ dst,
    const _Float16* __restrict__ w1b, const _Float16* __restrict__ w2b,
    const float* __restrict__ b1, const float* __restrict__ b2,
    const float* __restrict__ ln_g, const float* __restrict__ ln_b,
    float* __restrict__ fin, bool last, float alpha, float beta, float rwr,
    _Float16* cellsL, _Float16 (*arena)[64 * 136])
{
    int b = tile >> 7;
    int t0 = (tile & 127) << 6;
    const float* srcb = src + (size_t)b * TT * D;

    int tid = threadIdx.x;
    // stage cells tile (fp32 -> f16 LDS, RNE casts)
    for (int idx = tid; idx < 66 * 16; idx += 256) {
        int row = idx >> 4;
        int c4 = (idx & 15) << 2;
        int tok = (t0 - 1 + row) & (TT - 1);
        f32x4 v = *(const f32x4*)(srcb + (size_t)tok * D + c4);
        *(f16x4*)&cellsL[row * 72 + c4] = cvt4_rne(v[0], v[1], v[2], v[3]);
    }
    __syncthreads();   // barrier 1

    int wave = tid >> 6;       // = rule index
    int lane = tid & 63;
    int lrow = lane & 15;
    int lgrp = lane >> 4;
    int r = wave;

    const f16x8* w1v = (const f16x8*)w1b;
    const f16x8* w2v = (const f16x8*)w2b;
    _Float16* hb = &arena[wave][0];

    // ---- GEMM1: h^T = W1_r^T X^T  (128 hcols x 64 tokens)
    f32x4 acc1[8][4];
#pragma unroll
    for (int ht = 0; ht < 8; ++ht)
#pragma unroll
        for (int nt = 0; nt < 4; ++nt)
            acc1[ht][nt] = (f32x4){0.f, 0.f, 0.f, 0.f};

#pragma unroll
    for (int ks = 0; ks < 6; ++ks) {
        int k0 = ks * 32 + lgrp * 8;
        int seg = k0 >> 6;                     // 0:c[t] 1:c[t-1] 2:c[t+1]
        int kk = k0 & 63;
        int drow = (seg == 0) ? 1 : ((seg == 1) ? 0 : 2);
        f16x8 a_[4];
#pragma unroll
        for (int nt = 0; nt < 4; ++nt)
            a_[nt] = *(const f16x8*)&cellsL[(nt * 16 + lrow + drow) * 72 + kk];
#pragma unroll
        for (int ht = 0; ht < 8; ++ht) {
            f16x8 wf = w1v[(ks * 32 + r * 8 + ht) * 64 + lane];
#pragma unroll
            for (int nt = 0; nt < 4; ++nt)
                acc1[ht][nt] = __builtin_amdgcn_mfma_f32_16x16x32_f16(wf, a_[nt], acc1[ht][nt], 0, 0, 0);
        }
    }

    // gelu + wave-private H store (no barrier: same-wave LDS dependency)
#pragma unroll
    for (int ht = 0; ht < 8; ++ht) {
        f32x4 b1v = *(const f32x4*)&b1[r * HD + ht * 16 + lgrp * 4];
#pragma unroll
        for (int nt = 0; nt < 4; ++nt) {
            float g0 = gelu_tanh(acc1[ht][nt][0] + b1v[0]);
            float g1 = gelu_tanh(acc1[ht][nt][1] + b1v[1]);
            float g2 = gelu_tanh(acc1[ht][nt][2] + b1v[2]);
            float g3 = gelu_tanh(acc1[ht][nt][3] + b1v[3]);
            *(f16x4*)&hb[(nt * 16 + lrow) * 136 + ht * 16 + lgrp * 4]
                = cvt4_rne(g0, g1, g2, g3);
        }
    }

    // ---- GEMM2: out^T = W2_r^T H^T  (64 d x 64 tokens), wave-private
    f32x4 acc2[4][4];
#pragma unroll
    for (int mt = 0; mt < 4; ++mt)
#pragma unroll
        for (int nt = 0; nt < 4; ++nt)
            acc2[mt][nt] = (f32x4){0.f, 0.f, 0.f, 0.f};

#pragma unroll
    for (int ks2 = 0; ks2 < 4; ++ks2) {
        f16x8 a2[4];
#pragma unroll
        for (int nt = 0; nt < 4; ++nt)
            a2[nt] = *(const f16x8*)&hb[(nt * 16 + lrow) * 136 + ks2 * 32 + lgrp * 8];
#pragma unroll
        for (int mt = 0; mt < 4; ++mt) {
            f16x8 bw = w2v[((r * 4 + ks2) * 4 + mt) * 64 + lane];
#pragma unroll
            for (int nt = 0; nt < 4; ++nt)
                acc2[mt][nt] = __builtin_amdgcn_mfma_f32_16x16x32_f16(bw, a2[nt], acc2[mt][nt], 0, 0, 0);
        }
    }

    // tanh * rule_weight -> f32 mix slice in the SAME arena (H is dead now)
    float* mixw = (float*)hb;   // [64 tokens][stride 68 f32]
#pragma unroll
    for (int mt = 0; mt < 4; ++mt) {
        f32x4 b2v = *(const f32x4*)&b2[r * D + mt * 16 + lgrp * 4];
#pragma unroll
        for (int nt = 0; nt < 4; ++nt) {
            f32x4 o;
#pragma unroll
            for (int q = 0; q < 4; ++q)
                o[q] = rwr * fast_tanh(acc2[mt][nt][q] + b2v[q]);
            *(f32x4*)&mixw[(nt * 16 + lrow) * 68 + mt * 16 + lgrp * 4] = o;
        }
    }

    __syncthreads();   // barrier 2

    // ---- cross-rule reduce + alpha mix; thread -> (token, d-quarter)
    int tok = tid >> 2;                 // 0..63
    int dq = tid & 3;                   // d-quarter (16 contiguous d)
    const float* ar0 = (const float*)&arena[0][0];
    const float* ar1 = (const float*)&arena[1][0];
    const float* ar2 = (const float*)&arena[2][0];
    const float* ar3 = (const float*)&arena[3][0];
    int mbase = tok * 68 + dq * 16;
    size_t roff = (size_t)b * TT * D + (size_t)(t0 + tok) * D + dq * 16;

    f32x4 ov[4];
    float m0 = 0.f, m1 = 0.f;
#pragma unroll
    for (int j = 0; j < 4; ++j) {
        f32x4 v0 = *(const f32x4*)(ar0 + mbase + j * 4);
        f32x4 v1 = *(const f32x4*)(ar1 + mbase + j * 4);
        f32x4 v2 = *(const f32x4*)(ar2 + mbase + j * 4);
        f32x4 v3 = *(const f32x4*)(ar3 + mbase + j * 4);
        f32x4 s  = *(const f32x4*)(src + roff + j * 4);
#pragma unroll
        for (int q = 0; q < 4; ++q) {
            float v = alpha * s[q] + beta * (v0[q] + v1[q] + v2[q] + v3[q]);
            ov[j][q] = v; m0 += v; m1 += v * v;
        }
    }

    if (!last) {
#pragma unroll
        for (int j = 0; j < 4; ++j)
            *(f32x4*)(dst + roff + j * 4) = ov[j];
    } else {
        // fused LayerNorm: token's 64 d live in 4 consecutive lanes (dq 0-3)
        m0 += __shfl_xor(m0, 1, 64); m1 += __shfl_xor(m1, 1, 64);
        m0 += __shfl_xor(m0, 2, 64); m1 += __shfl_xor(m1, 2, 64);
        float mu = m0 * (1.0f / 64.0f);
        float inv = rsqrtf(m1 * (1.0f / 64.0f) - mu * mu + 1e-5f);
#pragma unroll
        for (int j = 0; j < 4; ++j) {
            f32x4 g4 = *(const f32x4*)&ln_g[dq * 16 + j * 4];
            f32x4 b4 = *(const f32x4*)&ln_b[dq * 16 + j * 4];
            f32x4 o;
#pragma unroll
            for (int q = 0; q < 4; ++q)
                o[q] = (ov[j][q] - mu) * inv * g4[q] + b4[q];
            *(f32x4*)(fin + roff + j * 4) = o;
        }
    }
}

// ---------------------------------------------------------------------------
// Evolve kernel R11: per-iteration launch (R8 scheme) with device-selected
// buffers using the backwards-parity schedule (verified in R10's megakernel):
//   dst(i) = ((n-2-i)&1)==0 ? bufA : out   => the LAST iteration's src is
// always bufA, so the fused-LN write to `out` can never alias its input.
// ---------------------------------------------------------------------------
__global__ __launch_bounds__(256, 2) void evolve_kernel(
    const float* __restrict__ cells, float* __restrict__ bufA,
    float* __restrict__ out, const float* __restrict__ ctrl,
    const _Float16* __restrict__ w1b, const _Float16* __restrict__ w2b,
    const float* __restrict__ b1, const float* __restrict__ b2,
    const float* __restrict__ ln_g, const float* __restrict__ ln_b, int iter)
{
    int n = (int)ctrl[5];
    if (iter >= n) return;
    bool last = (iter == n - 1);

    const float* src = (iter == 0) ? cells
                       : ((((n - 1 - iter) & 1) == 0) ? (const float*)bufA
                                                      : (const float*)out);
    float* dst = (((n - 2 - iter) & 1) == 0) ? bufA : out;  // unused if last

    __shared__ _Float16 cellsL[66 * 72];                     // 9504 B
    __shared__ __align__(16) _Float16 arena[4][64 * 136];    // 4 x 17408 B

    float alpha = ctrl[4];
    float rwr = ctrl[threadIdx.x >> 6];
    evolve_tile(blockIdx.x, src, dst, w1b, w2b, b1, b2, ln_g, ln_b,
                out, last, alpha, 1.0f - alpha, rwr, cellsL, arena);
}

// ---------------------------------------------------------------------------
extern "C" void kernel_launch(void* const* d_in, const int* in_sizes, int n_in,
                              void* d_out, int out_size, void* d_ws, size_t ws_size,
                              hipStream_t stream) {
    const float* cells   = (const float*)d_in[0];
    const float* c_state = (const float*)d_in[1];
    const float* rule_w1 = (const float*)d_in[2];
    const float* rule_b1 = (const float*)d_in[3];
    const float* rule_w2 = (const float*)d_in[4];
    const float* rule_b2 = (const float*)d_in[5];
    const float* sel_w1  = (const float*)d_in[6];
    const float* sel_b1  = (const float*)d_in[7];
    const float* sel_w2  = (const float*)d_in[8];
    const float* sel_b2  = (const float*)d_in[9];
    const float* st_w1   = (const float*)d_in[10];
    const float* st_b1   = (const float*)d_in[11];
    const float* st_w2   = (const float*)d_in[12];
    const float* st_b2   = (const float*)d_in[13];
    const float* res_w1  = (const float*)d_in[14];
    const float* res_b1  = (const float*)d_in[15];
    const float* res_w2  = (const float*)d_in[16];
    const float* res_b2  = (const float*)d_in[17];
    const float* ln_g    = (const float*)d_in[18];
    const float* ln_b    = (const float*)d_in[19];

    float* out = (float*)d_out;
    char* ws = (char*)d_ws;
    float* ctrl = (float*)ws;                              // 64 B
    _Float16* w1b = (_Float16*)(ws + 256);                 // 196608 B
    _Float16* w2b = (_Float16*)(ws + 256 + 196608);        // 65536 B
    float* bufA = (float*)(ws + (512u * 1024u));           // 64 MiB ping buffer

    prep_control_kernel<<<65, 256, 0, stream>>>(
        rule_w1, rule_w2, w1b, w2b, c_state,
        sel_w1, sel_b1, sel_w2, sel_b2,
        st_w1, st_b1, st_w2, st_b2,
        res_w1, res_b1, res_w2, res_b2, ctrl);

    // 8 potential iterations; dead ones early-exit on device. Buffers are
    // selected on-device (backwards parity); last live iteration applies
    // fused LayerNorm and writes d_out.
    for (int i = 0; i < 8; ++i) {
        evolve_kernel<<<4096, 256, 0, stream>>>(cells, bufA, out, ctrl,
                                                w1b, w2b, rule_b1, rule_b2,
                                                ln_g, ln_b, i);
    }
}

// Round 12
// 590.675 us; speedup vs baseline: 3.6847x; 1.0048x over previous
//
#include <hip/hip_runtime.h>
#include <cmath>

#define D 64
#define HD 128
#define K1 192
#define TT 8192
#define BBATCH 32
#define RULES 4

typedef _Float16 f16x8 __attribute__((ext_vector_type(8)));
typedef _Float16 f16x4 __attribute__((ext_vector_type(4)));
typedef float f32x4 __attribute__((ext_vector_type(4)));

__device__ __forceinline__ float gelu_exact(float x) {
    return 0.5f * x * (1.0f + erff(x * 0.70710678118654752f));
}

__device__ __forceinline__ float fast_rcp(float x) { return __builtin_amdgcn_rcpf(x); }
__device__ __forceinline__ float fast_exp2(float x) { return __builtin_amdgcn_exp2f(x); }

// tanh-approx GELU (R8, passing): ~6 VALU + 2 trans.
__device__ __forceinline__ float gelu_tanh(float x) {
    float x2 = x * x;
    float t = x * fmaf(x2, -0.10294443f, -2.30220820f);
    return x * fast_rcp(1.0f + fast_exp2(t));
}
// tanh(x) = 1 - 2/(exp2(2*log2e*x)+1) ; exact identity, saturates cleanly
__device__ __forceinline__ float fast_tanh(float x) {
    float e = fast_exp2(x * 2.8853900817779268f);
    return 1.0f - 2.0f * fast_rcp(e + 1.0f);
}

__device__ __forceinline__ f16x4 cvt4_rne(float a, float b, float c, float d) {
    f16x4 r;
    r[0] = (_Float16)a; r[1] = (_Float16)b;
    r[2] = (_Float16)c; r[3] = (_Float16)d;
    return r;
}

// ---------------------------------------------------------------------------
// Prep+control kernel: blocks 0..63 re-layout weights (verified R4-R10);
// block 64 computes rule_weights[4], alpha, n_evolve -> ctrl[0..5].
//   w1b: A-fragments of W1^T  [ks(6)][htile(32, = r*8+ht)][lane][8]
//   w2b: A-fragments of W2^T  [r][ks2][dtile(4)][lane][8]
// ---------------------------------------------------------------------------
__global__ __launch_bounds__(256) void prep_control_kernel(
    const float* __restrict__ rule_w1, const float* __restrict__ rule_w2,
    _Float16* __restrict__ w1b, _Float16* __restrict__ w2b,
    const float* __restrict__ c_state,
    const float* __restrict__ sel_w1, const float* __restrict__ sel_b1,
    const float* __restrict__ sel_w2, const float* __restrict__ sel_b2,
    const float* __restrict__ st_w1,  const float* __restrict__ st_b1,
    const float* __restrict__ st_w2,  const float* __restrict__ st_b2,
    const float* __restrict__ res_w1, const float* __restrict__ res_b1,
    const float* __restrict__ res_w2, const float* __restrict__ res_b2,
    float* __restrict__ ctrl)
{
    if (blockIdx.x < 64) {
        int t = blockIdx.x * 256 + threadIdx.x;
        if (t < 12288) {
            int lane = t & 63;
            int x = t >> 6;          // 0..191
            int htile = x & 31;      // global h tile (r = htile>>3)
            int ks = x >> 5;         // 0..5
            int r = htile >> 3;
            int h128 = (htile & 7) * 16 + (lane & 15);
            int kbase = ks * 32 + (lane >> 4) * 8;
            f16x8 v;
#pragma unroll
            for (int j = 0; j < 8; ++j)
                v[j] = (_Float16)rule_w1[((size_t)r * K1 + kbase + j) * HD + h128];
            ((f16x8*)w1b)[(ks * 32 + htile) * 64 + lane] = v;
        } else if (t < 12288 + 4096) {
            int u = t - 12288;
            int lane = u & 63;
            int mt = (u >> 6) & 3;   // d tile
            int ks2 = (u >> 8) & 3;  // hidden-k tile
            int r = u >> 10;
            int kbase = ks2 * 32 + (lane >> 4) * 8;
            int d = mt * 16 + (lane & 15);
            f16x8 v;
#pragma unroll
            for (int j = 0; j < 8; ++j)
                v[j] = (_Float16)rule_w2[((size_t)r * HD + kbase + j) * D + d];
            ((f16x8*)w2b)[((r * 4 + ks2) * 4 + mt) * 64 + lane] = v;
        }
        return;
    }

    // ---- control block (blockIdx.x == 64); all 256 threads hit barriers
    __shared__ float cs[128];
    __shared__ float h1s[64], h2s[32], h3s[32];
    __shared__ float lg[12];
    int l = threadIdx.x;
    if (l < 64) { cs[l] = c_state[l]; cs[l + 64] = c_state[l + 64]; }
    __syncthreads();
    if (l < 64) {
        float a = sel_b1[l];
        for (int k = 0; k < 128; ++k) a += cs[k] * sel_w1[k * 64 + l];
        h1s[l] = gelu_exact(a);
    }
    if (l < 32) {
        float a = st_b1[l];
        for (int k = 0; k < 128; ++k) a += cs[k] * st_w1[k * 32 + l];
        h2s[l] = gelu_exact(a);
        float a2 = res_b1[l];
        for (int k = 0; k < 128; ++k) a2 += cs[k] * res_w1[k * 32 + l];
        h3s[l] = gelu_exact(a2);
    }
    __syncthreads();
    if (l < 4) {
        float a = sel_b2[l];
        for (int j = 0; j < 64; ++j) a += h1s[j] * sel_w2[j * 4 + l];
        lg[l] = a;
    }
    if (l >= 8 && l < 15) {
        int s = l - 8;
        float a = st_b2[s];
        for (int j = 0; j < 32; ++j) a += h2s[j] * st_w2[j * 7 + s];
        lg[4 + s] = a;
    }
    if (l == 32) {
        float a = res_b2[0];
        for (int j = 0; j < 32; ++j) a += h3s[j] * res_w2[j];
        lg[11] = a;
    }
    __syncthreads();
    if (l == 0) {
        float m = fmaxf(fmaxf(lg[0], lg[1]), fmaxf(lg[2], lg[3]));
        float e0 = expf(lg[0] - m), e1 = expf(lg[1] - m);
        float e2 = expf(lg[2] - m), e3 = expf(lg[3] - m);
        float s = e0 + e1 + e2 + e3;
        ctrl[0] = e0 / s; ctrl[1] = e1 / s; ctrl[2] = e2 / s; ctrl[3] = e3 / s;
        float m2 = lg[4];
        for (int i = 1; i < 7; ++i) m2 = fmaxf(m2, lg[4 + i]);
        float ss = 0.f, es[7];
        for (int i = 0; i < 7; ++i) { es[i] = expf(lg[4 + i] - m2); ss += es[i]; }
        float nsoft = 0.f;
        for (int i = 0; i < 7; ++i) nsoft += (es[i] / ss) * (float)(i + 2);
        int n = (int)(nsoft + 0.5f);
        n = n < 2 ? 2 : (n > 8 ? 8 : n);
        float alpha = 0.1f + 0.8f / (1.0f + expf(-lg[11]));
        ctrl[4] = alpha;
        ctrl[5] = (float)n;
    }
}

// ---------------------------------------------------------------------------
// Device-side tile body (identical math/layout to R8; LN path verified R10).
// Processes one 64-token tile for one iteration. If `last`, applies fused
// LayerNorm and writes `fin`; otherwise writes alpha-mixed cells to `dst`.
// ---------------------------------------------------------------------------
__device__ __forceinline__ void evolve_tile(
    int tile, const float* __restrict__ src, float* __restrict__ dst,
    const _Float16* __restrict__ w1b, const _Float16* __restrict__ w2b,
    const float* __restrict__ b1, const float* __restrict__ b2,
    const float* __restrict__ ln_g, const float* __restrict__ ln_b,
    float* __restrict__ fin, bool last, float alpha, float beta, float rwr,
    _Float16* cellsL, _Float16 (*arena)[64 * 136])
{
    int b = tile >> 7;
    int t0 = (tile & 127) << 6;
    const float* srcb = src + (size_t)b * TT * D;

    int tid = threadIdx.x;
    // stage cells tile (fp32 -> f16 LDS, RNE casts)
    for (int idx = tid; idx < 66 * 16; idx += 256) {
        int row = idx >> 4;
        int c4 = (idx & 15) << 2;
        int tok = (t0 - 1 + row) & (TT - 1);
        f32x4 v = *(const f32x4*)(srcb + (size_t)tok * D + c4);
        *(f16x4*)&cellsL[row * 72 + c4] = cvt4_rne(v[0], v[1], v[2], v[3]);
    }
    __syncthreads();   // barrier 1

    int wave = tid >> 6;       // = rule index
    int lane = tid & 63;
    int lrow = lane & 15;
    int lgrp = lane >> 4;
    int r = wave;

    const f16x8* w1v = (const f16x8*)w1b;
    const f16x8* w2v = (const f16x8*)w2b;
    _Float16* hb = &arena[wave][0];

    // ---- GEMM1: h^T = W1_r^T X^T  (128 hcols x 64 tokens)
    f32x4 acc1[8][4];
#pragma unroll
    for (int ht = 0; ht < 8; ++ht)
#pragma unroll
        for (int nt = 0; nt < 4; ++nt)
            acc1[ht][nt] = (f32x4){0.f, 0.f, 0.f, 0.f};

#pragma unroll
    for (int ks = 0; ks < 6; ++ks) {
        int k0 = ks * 32 + lgrp * 8;
        int seg = k0 >> 6;                     // 0:c[t] 1:c[t-1] 2:c[t+1]
        int kk = k0 & 63;
        int drow = (seg == 0) ? 1 : ((seg == 1) ? 0 : 2);
        f16x8 a_[4];
#pragma unroll
        for (int nt = 0; nt < 4; ++nt)
            a_[nt] = *(const f16x8*)&cellsL[(nt * 16 + lrow + drow) * 72 + kk];
#pragma unroll
        for (int ht = 0; ht < 8; ++ht) {
            f16x8 wf = w1v[(ks * 32 + r * 8 + ht) * 64 + lane];
#pragma unroll
            for (int nt = 0; nt < 4; ++nt)
                acc1[ht][nt] = __builtin_amdgcn_mfma_f32_16x16x32_f16(wf, a_[nt], acc1[ht][nt], 0, 0, 0);
        }
    }

    // gelu + wave-private H store (no barrier: same-wave LDS dependency)
#pragma unroll
    for (int ht = 0; ht < 8; ++ht) {
        f32x4 b1v = *(const f32x4*)&b1[r * HD + ht * 16 + lgrp * 4];
#pragma unroll
        for (int nt = 0; nt < 4; ++nt) {
            float g0 = gelu_tanh(acc1[ht][nt][0] + b1v[0]);
            float g1 = gelu_tanh(acc1[ht][nt][1] + b1v[1]);
            float g2 = gelu_tanh(acc1[ht][nt][2] + b1v[2]);
            float g3 = gelu_tanh(acc1[ht][nt][3] + b1v[3]);
            *(f16x4*)&hb[(nt * 16 + lrow) * 136 + ht * 16 + lgrp * 4]
                = cvt4_rne(g0, g1, g2, g3);
        }
    }

    // ---- GEMM2: out^T = W2_r^T H^T  (64 d x 64 tokens), wave-private
    f32x4 acc2[4][4];
#pragma unroll
    for (int mt = 0; mt < 4; ++mt)
#pragma unroll
        for (int nt = 0; nt < 4; ++nt)
            acc2[mt][nt] = (f32x4){0.f, 0.f, 0.f, 0.f};

#pragma unroll
    for (int ks2 = 0; ks2 < 4; ++ks2) {
        f16x8 a2[4];
#pragma unroll
        for (int nt = 0; nt < 4; ++nt)
            a2[nt] = *(const f16x8*)&hb[(nt * 16 + lrow) * 136 + ks2 * 32 + lgrp * 8];
#pragma unroll
        for (int mt = 0; mt < 4; ++mt) {
            f16x8 bw = w2v[((r * 4 + ks2) * 4 + mt) * 64 + lane];
#pragma unroll
            for (int nt = 0; nt < 4; ++nt)
                acc2[mt][nt] = __builtin_amdgcn_mfma_f32_16x16x32_f16(bw, a2[nt], acc2[mt][nt], 0, 0, 0);
        }
    }

    // tanh * rule_weight -> f32 mix slice in the SAME arena (H is dead now)
    float* mixw = (float*)hb;   // [64 tokens][stride 68 f32]
#pragma unroll
    for (int mt = 0; mt < 4; ++mt) {
        f32x4 b2v = *(const f32x4*)&b2[r * D + mt * 16 + lgrp * 4];
#pragma unroll
        for (int nt = 0; nt < 4; ++nt) {
            f32x4 o;
#pragma unroll
            for (int q = 0; q < 4; ++q)
                o[q] = rwr * fast_tanh(acc2[mt][nt][q] + b2v[q]);
            *(f32x4*)&mixw[(nt * 16 + lrow) * 68 + mt * 16 + lgrp * 4] = o;
        }
    }

    __syncthreads();   // barrier 2

    // ---- cross-rule reduce + alpha mix; thread -> (token, d-quarter)
    int tok = tid >> 2;                 // 0..63
    int dq = tid & 3;                   // d-quarter (16 contiguous d)
    const float* ar0 = (const float*)&arena[0][0];
    const float* ar1 = (const float*)&arena[1][0];
    const float* ar2 = (const float*)&arena[2][0];
    const float* ar3 = (const float*)&arena[3][0];
    int mbase = tok * 68 + dq * 16;
    size_t roff = (size_t)b * TT * D + (size_t)(t0 + tok) * D + dq * 16;

    f32x4 ov[4];
    float m0 = 0.f, m1 = 0.f;
#pragma unroll
    for (int j = 0; j < 4; ++j) {
        f32x4 v0 = *(const f32x4*)(ar0 + mbase + j * 4);
        f32x4 v1 = *(const f32x4*)(ar1 + mbase + j * 4);
        f32x4 v2 = *(const f32x4*)(ar2 + mbase + j * 4);
        f32x4 v3 = *(const f32x4*)(ar3 + mbase + j * 4);
        f32x4 s  = *(const f32x4*)(src + roff + j * 4);
#pragma unroll
        for (int q = 0; q < 4; ++q) {
            float v = alpha * s[q] + beta * (v0[q] + v1[q] + v2[q] + v3[q]);
            ov[j][q] = v; m0 += v; m1 += v * v;
        }
    }

    if (!last) {
#pragma unroll
        for (int j = 0; j < 4; ++j)
            *(f32x4*)(dst + roff + j * 4) = ov[j];
    } else {
        // fused LayerNorm: token's 64 d live in 4 consecutive lanes (dq 0-3)
        m0 += __shfl_xor(m0, 1, 64); m1 += __shfl_xor(m1, 1, 64);
        m0 += __shfl_xor(m0, 2, 64); m1 += __shfl_xor(m1, 2, 64);
        float mu = m0 * (1.0f / 64.0f);
        float inv = rsqrtf(m1 * (1.0f / 64.0f) - mu * mu + 1e-5f);
#pragma unroll
        for (int j = 0; j < 4; ++j) {
            f32x4 g4 = *(const f32x4*)&ln_g[dq * 16 + j * 4];
            f32x4 b4 = *(const f32x4*)&ln_b[dq * 16 + j * 4];
            f32x4 o;
#pragma unroll
            for (int q = 0; q < 4; ++q)
                o[q] = (ov[j][q] - mu) * inv * g4[q] + b4[q];
            *(f32x4*)(fin + roff + j * 4) = o;
        }
    }
}

// ---------------------------------------------------------------------------
// Evolve kernel R11: per-iteration launch (R8 scheme) with device-selected
// buffers using the backwards-parity schedule (verified in R10's megakernel):
//   dst(i) = ((n-2-i)&1)==0 ? bufA : out   => the LAST iteration's src is
// always bufA, so the fused-LN write to `out` can never alias its input.
// ---------------------------------------------------------------------------
__global__ __launch_bounds__(256, 2) void evolve_kernel(
    const float* __restrict__ cells, float* __restrict__ bufA,
    float* __restrict__ out, const float* __restrict__ ctrl,
    const _Float16* __restrict__ w1b, const _Float16* __restrict__ w2b,
    const float* __restrict__ b1, const float* __restrict__ b2,
    const float* __restrict__ ln_g, const float* __restrict__ ln_b, int iter)
{
    int n = (int)ctrl[5];
    if (iter >= n) return;
    bool last = (iter == n - 1);

    const float* src = (iter == 0) ? cells
                       : ((((n - 1 - iter) & 1) == 0) ? (const float*)bufA
                                                      : (const float*)out);
    float* dst = (((n - 2 - iter) & 1) == 0) ? bufA : out;  // unused if last

    __shared__ _Float16 cellsL[66 * 72];                     // 9504 B
    __shared__ __align__(16) _Float16 arena[4][64 * 136];    // 4 x 17408 B

    float alpha = ctrl[4];
    float rwr = ctrl[threadIdx.x >> 6];
    evolve_tile(blockIdx.x, src, dst, w1b, w2b, b1, b2, ln_g, ln_b,
                out, last, alpha, 1.0f - alpha, rwr, cellsL, arena);
}

// ---------------------------------------------------------------------------
extern "C" void kernel_launch(void* const* d_in, const int* in_sizes, int n_in,
                              void* d_out, int out_size, void* d_ws, size_t ws_size,
                              hipStream_t stream) {
    const float* cells   = (const float*)d_in[0];
    const float* c_state = (const float*)d_in[1];
    const float* rule_w1 = (const float*)d_in[2];
    const float* rule_b1 = (const float*)d_in[3];
    const float* rule_w2 = (const float*)d_in[4];
    const float* rule_b2 = (const float*)d_in[5];
    const float* sel_w1  = (const float*)d_in[6];
    const float* sel_b1  = (const float*)d_in[7];
    const float* sel_w2  = (const float*)d_in[8];
    const float* sel_b2  = (const float*)d_in[9];
    const float* st_w1   = (const float*)d_in[10];
    const float* st_b1   = (const float*)d_in[11];
    const float* st_w2   = (const float*)d_in[12];
    const float* st_b2   = (const float*)d_in[13];
    const float* res_w1  = (const float*)d_in[14];
    const float* res_b1  = (const float*)d_in[15];
    const float* res_w2  = (const float*)d_in[16];
    const float* res_b2  = (const float*)d_in[17];
    const float* ln_g    = (const float*)d_in[18];
    const float* ln_b    = (const float*)d_in[19];

    float* out = (float*)d_out;
    char* ws = (char*)d_ws;
    float* ctrl = (float*)ws;                              // 64 B
    _Float16* w1b = (_Float16*)(ws + 256);                 // 196608 B
    _Float16* w2b = (_Float16*)(ws + 256 + 196608);        // 65536 B
    float* bufA = (float*)(ws + (512u * 1024u));           // 64 MiB ping buffer

    prep_control_kernel<<<65, 256, 0, stream>>>(
        rule_w1, rule_w2, w1b, w2b, c_state,
        sel_w1, sel_b1, sel_w2, sel_b2,
        st_w1, st_b1, st_w2, st_b2,
        res_w1, res_b1, res_w2, res_b2, ctrl);

    // 8 potential iterations; dead ones early-exit on device. Buffers are
    // selected on-device (backwards parity); last live iteration applies
    // fused LayerNorm and writes d_out.
    for (int i = 0; i < 8; ++i) {
        evolve_kernel<<<4096, 256, 0, stream>>>(cells, bufA, out, ctrl,
                                                w1b, w2b, rule_b1, rule_b2,
                                                ln_g, ln_b, i);
    }
}